// Round 3
// baseline (157.641 us; speedup 1.0000x reference)
//
#include <hip/hip_runtime.h>
#include <hip/hip_bf16.h>

// MSEL_Feat: fused per-identity loss, two-phase (partial sums + epilogue).
//   N=8192, D=2048, num_pos=4, id_num=2048.
//   Per identity, everything derives from 25 scalars:
//     rr[p]=|r_p|^2, ii[p]=|ir_p|^2, sr[p]=S.r_p, si[p]=S.ir_p,
//     ri[p]=r_p.ir_p, rt[p]=r_p.T, tt=|T|^2   (S=sum_p r_p, T=sum_p ir_p)
//   All are column-local dot products -> split D across 2 blocks/identity
//   for 2x oversubscription (4096 blocks vs 2048-block machine capacity),
//   single load phase per thread, atomicAdd partials into ws[25][id_num].

constexpr int D    = 2048;
constexpr int NPOS = 4;
constexpr int TPB  = 256;
constexpr int NACC = 25;
constexpr int SPLIT = 2;          // column chunks per identity (TPB float4 each)

__global__ void __launch_bounds__(TPB) msel_partial_kernel(
        const float* __restrict__ in1,   // RGB feats [N, D]
        const float* __restrict__ in2,   // IR  feats [N, D]
        float* __restrict__ ws,          // [NACC][id_num] partial sums (zeroed)
        int id_num) {
    const int b  = blockIdx.x;
    const int id = b >> 1;              // adjacent blocks share an identity ->
    const int hf = b & 1;               // adjacent 4KB column-halves per row
    const float* __restrict__ ra = in1 + (long)id * (NPOS * D);
    const float* __restrict__ rb = in2 + (long)id * (NPOS * D);
    const int c = (hf * TPB + threadIdx.x) * 4;   // float offset in row

    // single load phase: 8 independent float4 loads
    float rv[NPOS][4], iv[NPOS][4];
#pragma unroll
    for (int p = 0; p < NPOS; ++p) {
        *reinterpret_cast<float4*>(&rv[p][0]) =
            *reinterpret_cast<const float4*>(ra + p * D + c);
        *reinterpret_cast<float4*>(&iv[p][0]) =
            *reinterpret_cast<const float4*>(rb + p * D + c);
    }

    float acc[NACC];
#pragma unroll
    for (int k = 0; k < NACC; ++k) acc[k] = 0.0f;

#pragma unroll
    for (int e = 0; e < 4; ++e) {
        const float s = rv[0][e] + rv[1][e] + rv[2][e] + rv[3][e];
        const float t = iv[0][e] + iv[1][e] + iv[2][e] + iv[3][e];
        acc[24] = fmaf(t, t, acc[24]);                 // |T|^2
#pragma unroll
        for (int p = 0; p < NPOS; ++p) {
            const float x = rv[p][e];
            const float y = iv[p][e];
            acc[0  + p] = fmaf(x, x, acc[0  + p]);     // rr
            acc[4  + p] = fmaf(y, y, acc[4  + p]);     // ii
            acc[8  + p] = fmaf(s, x, acc[8  + p]);     // sr
            acc[12 + p] = fmaf(s, y, acc[12 + p]);     // si
            acc[16 + p] = fmaf(x, y, acc[16 + p]);     // ri
            acc[20 + p] = fmaf(x, t, acc[20 + p]);     // rt
        }
    }

    // 64-lane wave reduce each accumulator
#pragma unroll
    for (int k = 0; k < NACC; ++k) {
        float v = acc[k];
#pragma unroll
        for (int off = 32; off > 0; off >>= 1) v += __shfl_down(v, off, 64);
        acc[k] = v;
    }

    __shared__ float lds[TPB / 64][NACC];
    const int wave = threadIdx.x >> 6;
    const int lane = threadIdx.x & 63;
    if (lane == 0) {
#pragma unroll
        for (int k = 0; k < NACC; ++k) lds[wave][k] = acc[k];
    }
    __syncthreads();

    if (threadIdx.x < NACC) {
        const int k = threadIdx.x;
        const float tot = lds[0][k] + lds[1][k] + lds[2][k] + lds[3][k];
        atomicAdd(ws + k * id_num + id, tot);
    }
}

__global__ void __launch_bounds__(TPB) msel_epilogue_kernel(
        const float* __restrict__ ws, float* __restrict__ out, int id_num) {
    const int id = blockIdx.x * TPB + threadIdx.x;
    float contrib = 0.0f;
    if (id < id_num) {
        float tot[NACC];
#pragma unroll
        for (int k = 0; k < NACC; ++k) tot[k] = ws[k * id_num + id];  // coalesced

        const float ss = tot[8] + tot[9] + tot[10] + tot[11];  // |S|^2
        const float tt = tot[24];                              // |T|^2
#pragma unroll
        for (int p = 0; p < NPOS; ++p) {
            const float rr = tot[0 + p];
            const float ii = tot[4 + p];
            const float sr = tot[8 + p];
            const float si = tot[12 + p];
            const float ri = tot[16 + p];
            const float rt = tot[20 + p];

            // |loo_p|^2 = (|S|^2 - 2 S.r_p + |r_p|^2)/9
            const float b2loo = (ss - 2.0f * sr + rr) * (1.0f / 9.0f);
            const float sq_intra_rgb = rr + b2loo - 2.0f * ((sr - rr) * (1.0f / 3.0f));
            const float sq_intra_ir  = ii + b2loo - 2.0f * ((si - ri) * (1.0f / 3.0f));
            const float sq_cross_rgb = rr + tt * 0.0625f - 0.5f * rt;
            const float sq_cross_ir  = ii + ss * 0.0625f - 0.5f * si;

            const float d_ir_rgb = sqrtf(fmaxf(sq_intra_rgb, 1e-12f));
            const float d_ir_ir  = sqrtf(fmaxf(sq_intra_ir,  1e-12f));
            const float d_cr_rgb = sqrtf(fmaxf(sq_cross_rgb, 1e-12f));
            const float d_cr_ir  = sqrtf(fmaxf(sq_cross_ir,  1e-12f));

            const float e1 = d_cr_rgb - d_ir_rgb;
            const float e2 = d_cr_ir  - d_ir_ir;
            contrib += e1 * e1 + e2 * e2;
        }
        contrib *= (1.0f / 16384.0f);   // /N/2, N=8192
    }

    // block-reduce contrib, one atomic per block
#pragma unroll
    for (int off = 32; off > 0; off >>= 1) contrib += __shfl_down(contrib, off, 64);
    __shared__ float lds[TPB / 64];
    const int wave = threadIdx.x >> 6;
    if ((threadIdx.x & 63) == 0) lds[wave] = contrib;
    __syncthreads();
    if (threadIdx.x == 0) {
        float v = lds[0] + lds[1] + lds[2] + lds[3];
        atomicAdd(out, v);
    }
}

extern "C" void kernel_launch(void* const* d_in, const int* in_sizes, int n_in,
                              void* d_out, int out_size, void* d_ws, size_t ws_size,
                              hipStream_t stream) {
    const float* in1 = (const float*)d_in[0];
    const float* in2 = (const float*)d_in[1];
    float* out = (float*)d_out;
    float* ws  = (float*)d_ws;

    const int id_num = in_sizes[0] / (NPOS * D);   // 2048

    hipMemsetAsync(ws, 0, (size_t)NACC * id_num * sizeof(float), stream);
    hipMemsetAsync(out, 0, sizeof(float), stream);

    msel_partial_kernel<<<id_num * SPLIT, TPB, 0, stream>>>(in1, in2, ws, id_num);
    msel_epilogue_kernel<<<(id_num + TPB - 1) / TPB, TPB, 0, stream>>>(ws, out, id_num);
}

// Round 5
// 148.328 us; speedup vs baseline: 1.0628x; 1.0628x over previous
//
#include <hip/hip_runtime.h>
#include <hip/hip_bf16.h>

// MSEL_Feat: fused per-identity loss, single pass.
//   N=8192, D=2048, num_pos=4, id_num=2048.
//   Per identity, everything derives from 25 scalars:
//     rr[p]=|r_p|^2, ii[p]=|ir_p|^2, sr[p]=S.r_p, si[p]=S.ir_p,
//     ri[p]=r_p.ir_p, rt[p]=r_p.T, tt=|T|^2   (S=sum_p r_p, T=sum_p ir_p)
//
// Round-3 lesson: VGPR_Count=32 -> compiler serialized the loads, ~2 in
// flight per wave -> latency-bound at 1.4 TB/s. This version hoists ALL 16
// float4 loads (16 KB/wave in flight) with __launch_bounds__(256,2) giving
// the allocator a 256-VGPR budget. One block per identity, each thread owns
// 8 columns (tid*4 and tid*4+1024).

constexpr int D    = 2048;
constexpr int NPOS = 4;
constexpr int TPB  = 256;
constexpr int NACC = 25;

__global__ void zero_out_kernel(float* out) { out[0] = 0.0f; }

__global__ void __launch_bounds__(TPB, 2) msel_feat_kernel(
        const float* __restrict__ in1,   // RGB feats [N, D]
        const float* __restrict__ in2,   // IR  feats [N, D]
        float* __restrict__ out) {
    const long id = blockIdx.x;
    const float* __restrict__ ra = in1 + id * (long)(NPOS * D);
    const float* __restrict__ rb = in2 + id * (long)(NPOS * D);
    const int c0 = threadIdx.x * 4;          // first column group
    const int c1 = threadIdx.x * 4 + 1024;   // second column group

    // ---- issue ALL 16 independent float4 loads up front (max MLP) ----
    float4 rA[NPOS], rB[NPOS], iA[NPOS], iB[NPOS];
#pragma unroll
    for (int p = 0; p < NPOS; ++p) rA[p] = *reinterpret_cast<const float4*>(ra + p * D + c0);
#pragma unroll
    for (int p = 0; p < NPOS; ++p) rB[p] = *reinterpret_cast<const float4*>(ra + p * D + c1);
#pragma unroll
    for (int p = 0; p < NPOS; ++p) iA[p] = *reinterpret_cast<const float4*>(rb + p * D + c0);
#pragma unroll
    for (int p = 0; p < NPOS; ++p) iB[p] = *reinterpret_cast<const float4*>(rb + p * D + c1);

    float acc[NACC];
#pragma unroll
    for (int k = 0; k < NACC; ++k) acc[k] = 0.0f;

#pragma unroll
    for (int g = 0; g < 2; ++g) {
        const float4* rv = (g == 0) ? rA : rB;
        const float4* iv = (g == 0) ? iA : iB;
#pragma unroll
        for (int e = 0; e < 4; ++e) {
            const float r0 = (&rv[0].x)[e], r1 = (&rv[1].x)[e],
                        r2 = (&rv[2].x)[e], r3 = (&rv[3].x)[e];
            const float i0 = (&iv[0].x)[e], i1 = (&iv[1].x)[e],
                        i2 = (&iv[2].x)[e], i3 = (&iv[3].x)[e];
            const float s = r0 + r1 + r2 + r3;
            const float t = i0 + i1 + i2 + i3;
            const float x[NPOS] = {r0, r1, r2, r3};
            const float y[NPOS] = {i0, i1, i2, i3};
            acc[24] = fmaf(t, t, acc[24]);                 // |T|^2
#pragma unroll
            for (int p = 0; p < NPOS; ++p) {
                acc[0  + p] = fmaf(x[p], x[p], acc[0  + p]);  // rr
                acc[4  + p] = fmaf(y[p], y[p], acc[4  + p]);  // ii
                acc[8  + p] = fmaf(s,    x[p], acc[8  + p]);  // sr
                acc[12 + p] = fmaf(s,    y[p], acc[12 + p]);  // si
                acc[16 + p] = fmaf(x[p], y[p], acc[16 + p]);  // ri
                acc[20 + p] = fmaf(x[p], t,    acc[20 + p]);  // rt
            }
        }
    }

    // ---- 64-lane wave reduce each accumulator ----
#pragma unroll
    for (int k = 0; k < NACC; ++k) {
        float v = acc[k];
#pragma unroll
        for (int off = 32; off > 0; off >>= 1) v += __shfl_down(v, off, 64);
        acc[k] = v;
    }

    __shared__ float lds[TPB / 64][NACC];
    const int wave = threadIdx.x >> 6;
    const int lane = threadIdx.x & 63;
    if (lane == 0) {
#pragma unroll
        for (int k = 0; k < NACC; ++k) lds[wave][k] = acc[k];
    }
    __syncthreads();

    if (threadIdx.x == 0) {
        float tot[NACC];
#pragma unroll
        for (int k = 0; k < NACC; ++k)
            tot[k] = lds[0][k] + lds[1][k] + lds[2][k] + lds[3][k];

        const float ss = tot[8] + tot[9] + tot[10] + tot[11];  // |S|^2
        const float tt = tot[24];                              // |T|^2
        float contrib = 0.0f;
#pragma unroll
        for (int p = 0; p < NPOS; ++p) {
            const float rr = tot[0 + p];
            const float ii = tot[4 + p];
            const float sr = tot[8 + p];
            const float si = tot[12 + p];
            const float ri = tot[16 + p];
            const float rt = tot[20 + p];

            // |loo_p|^2 = (|S|^2 - 2 S.r_p + |r_p|^2)/9
            const float b2loo = (ss - 2.0f * sr + rr) * (1.0f / 9.0f);
            const float sq_intra_rgb = rr + b2loo - 2.0f * ((sr - rr) * (1.0f / 3.0f));
            const float sq_intra_ir  = ii + b2loo - 2.0f * ((si - ri) * (1.0f / 3.0f));
            const float sq_cross_rgb = rr + tt * 0.0625f - 0.5f * rt;
            const float sq_cross_ir  = ii + ss * 0.0625f - 0.5f * si;

            const float d_ir_rgb = sqrtf(fmaxf(sq_intra_rgb, 1e-12f));
            const float d_ir_ir  = sqrtf(fmaxf(sq_intra_ir,  1e-12f));
            const float d_cr_rgb = sqrtf(fmaxf(sq_cross_rgb, 1e-12f));
            const float d_cr_ir  = sqrtf(fmaxf(sq_cross_ir,  1e-12f));

            const float e1 = d_cr_rgb - d_ir_rgb;
            const float e2 = d_cr_ir  - d_ir_ir;
            contrib += e1 * e1 + e2 * e2;
        }
        // loss = sum / N / 2, N = 8192
        atomicAdd(out, contrib * (1.0f / 16384.0f));
    }
}

extern "C" void kernel_launch(void* const* d_in, const int* in_sizes, int n_in,
                              void* d_out, int out_size, void* d_ws, size_t ws_size,
                              hipStream_t stream) {
    const float* in1 = (const float*)d_in[0];
    const float* in2 = (const float*)d_in[1];
    float* out = (float*)d_out;

    const int id_num = in_sizes[0] / (NPOS * D);   // 2048

    zero_out_kernel<<<1, 1, 0, stream>>>(out);
    msel_feat_kernel<<<id_num, TPB, 0, stream>>>(in1, in2, out);
}